// Round 3
// baseline (195.418 us; speedup 1.0000x reference)
//
#include <hip/hip_runtime.h>

// HybridLoss: param smooth-L1 mean + 0.5*(1 - mean(box overlap))
// B = 2,000,000 rows x 10 f32 params (c[3], d[3], q[4]) for preds & targets.

#define B_ROWS 2000000
#define N_PARAM 10
constexpr float OVERLAP_WEIGHT = 0.5f;
constexpr float EPS_F = 1e-6f;

__device__ __forceinline__ void quat_to_rot(float x, float y, float z, float w,
                                            float R[9]) {
    R[0] = 1.f - 2.f*y*y - 2.f*z*z;
    R[1] = 2.f*x*y + 2.f*z*w;
    R[2] = 2.f*x*z - 2.f*y*w;
    R[3] = 2.f*x*y - 2.f*z*w;
    R[4] = 1.f - 2.f*x*x - 2.f*z*z;
    R[5] = 2.f*y*z + 2.f*x*w;
    R[6] = 2.f*x*z + 2.f*y*w;
    R[7] = 2.f*y*z - 2.f*x*w;
    R[8] = 1.f - 2.f*x*x - 2.f*y*y;
}

__global__ __launch_bounds__(256) void hybrid_loss_main(
    const float* __restrict__ preds, const float* __restrict__ targets,
    float* __restrict__ acc)  // acc[0] = smooth-L1 sum, acc[1] = overlap sum
{
    float psum = 0.f;
    float osum = 0.f;
    const int stride = gridDim.x * blockDim.x;
    for (int row = blockIdx.x * blockDim.x + threadIdx.x; row < B_ROWS; row += stride) {
        // rows are 40 B -> 8 B aligned; load as 5x float2 each
        const float2* pp = reinterpret_cast<const float2*>(preds   + (size_t)row * N_PARAM);
        const float2* tp = reinterpret_cast<const float2*>(targets + (size_t)row * N_PARAM);
        float p[10], t[10];
        #pragma unroll
        for (int i = 0; i < 5; ++i) {
            float2 a = pp[i]; p[2*i] = a.x; p[2*i+1] = a.y;
            float2 b = tp[i]; t[2*i] = b.x; t[2*i+1] = b.y;
        }

        // ---- smooth L1 over all 10 params ----
        #pragma unroll
        for (int i = 0; i < 10; ++i) {
            float d  = p[i] - t[i];
            float ad = fabsf(d);
            psum += (ad < 1.f) ? 0.5f * d * d : ad - 0.5f;
        }

        // ---- overlap ----
        // normalize quaternions
        float pqn = sqrtf(p[6]*p[6] + p[7]*p[7] + p[8]*p[8] + p[9]*p[9]);
        float tqn = sqrtf(t[6]*t[6] + t[7]*t[7] + t[8]*t[8] + t[9]*t[9]);
        float pri = 1.f / pqn, tri = 1.f / tqn;
        float PR[9], TR[9];
        quat_to_rot(p[6]*pri, p[7]*pri, p[8]*pri, p[9]*pri, PR);
        quat_to_rot(t[6]*tri, t[7]*tri, t[8]*tri, t[9]*tri, TR);

        // rotation alignment
        float ra = 0.f;
        #pragma unroll
        for (int i = 0; i < 9; ++i) ra += PR[i] * TR[i];
        ra = fminf(fmaxf(ra * (1.f/3.f), 0.f), 1.f);

        // extents: |R @ (d/2)| per axis, then per-axis overlap
        float ov = ra;
        #pragma unroll
        for (int i = 0; i < 3; ++i) {
            float pe = fabsf(PR[3*i+0]*(p[3]*0.5f) + PR[3*i+1]*(p[4]*0.5f) + PR[3*i+2]*(p[5]*0.5f));
            float te = fabsf(TR[3*i+0]*(t[3]*0.5f) + TR[3*i+1]*(t[4]*0.5f) + TR[3*i+2]*(t[5]*0.5f));
            float cd = fabsf(p[i] - t[i]);
            float ax = fmaxf(fminf(pe, te) * 2.f - cd, 0.f) / (pe + te + EPS_F);
            ov *= ax;
        }
        ov = fminf(fmaxf(ov, 0.f), 1.f);
        osum += ov;
    }

    // ---- wave64 reduction ----
    #pragma unroll
    for (int off = 32; off > 0; off >>= 1) {
        psum += __shfl_down(psum, off);
        osum += __shfl_down(osum, off);
    }
    __shared__ float sp[4], so[4];
    const int lane = threadIdx.x & 63;
    const int wid  = threadIdx.x >> 6;
    if (lane == 0) { sp[wid] = psum; so[wid] = osum; }
    __syncthreads();
    if (threadIdx.x == 0) {
        float P = sp[0] + sp[1] + sp[2] + sp[3];
        float O = so[0] + so[1] + so[2] + so[3];
        atomicAdd(&acc[0], P);
        atomicAdd(&acc[1], O);
    }
}

__global__ void hybrid_loss_finalize(const float* __restrict__ acc,
                                     float* __restrict__ out) {
    out[0] = acc[0] * (1.f / (10.f * (float)B_ROWS))
           + OVERLAP_WEIGHT * (1.f - acc[1] * (1.f / (float)B_ROWS));
}

extern "C" void kernel_launch(void* const* d_in, const int* in_sizes, int n_in,
                              void* d_out, int out_size, void* d_ws, size_t ws_size,
                              hipStream_t stream) {
    const float* preds   = (const float*)d_in[0];
    const float* targets = (const float*)d_in[1];
    float* out = (float*)d_out;
    float* acc = (float*)d_ws;

    hipMemsetAsync(acc, 0, 2 * sizeof(float), stream);

    const int block = 256;
    const int grid  = 2048;  // ~8 blocks/CU, grid-stride over 2M rows
    hybrid_loss_main<<<grid, block, 0, stream>>>(preds, targets, acc);
    hybrid_loss_finalize<<<1, 1, 0, stream>>>(acc, out);
}